// Round 9
// baseline (2819.587 us; speedup 1.0000x reference)
//
#include <hip/hip_runtime.h>
#include <math.h>

#define SC 4
#define BB 2
#define CC 32
#define HH 256
#define WW 512
#define CH (HH / SC)   // 64
#define CW (WW / SC)   // 128

// Direction metadata (output channel order: c, l, r, t, b, lt, rt, lb, rb)
//   s0: 0 -> xv (x[w%4]), 1 -> 4-(w%4) (D1), 2 -> (w%4)+1 (D2)
//   s1: 0 -> yv (x[h%4]), 1 -> 4-(h%4) (D3), 2 -> (h%4)+1 (D4)
// Diagonals reuse D1..D4 which modify ONLY ONE channel each.  [verified R2]
__device__ __constant__ int c_dh[9] = {0, 0, 0, -1, 1, -1, -1, 1, 1};
__device__ __constant__ int c_dw[9] = {0, -1, 1, 0, 0, -1, 1, -1, 1};
__device__ __constant__ int c_s0[9] = {0, 1, 2, 0, 0, 1, 2, 0, 0};
__device__ __constant__ int c_s1[9] = {0, 0, 0, 1, 2, 0, 0, 1, 2};

__device__ __forceinline__ float h2f_lo(unsigned u) {
    return (float)__builtin_bit_cast(_Float16, (unsigned short)(u & 0xffffu));
}
__device__ __forceinline__ float h2f_hi(unsigned u) {
    return (float)__builtin_bit_cast(_Float16, (unsigned short)(u >> 16));
}
__device__ __forceinline__ unsigned f2h2(float a, float b) {
    unsigned lo = (unsigned)__builtin_bit_cast(unsigned short, (_Float16)a);
    unsigned hi = (unsigned)__builtin_bit_cast(unsigned short, (_Float16)b);
    return lo | (hi << 16);
}

// Packed-weight layout in ws (u32 indices):
//   [0,512)   w0hr: row o (o<32), k<16 -> (w0[o*66+32+2k], w0[o*66+33+2k])
//   [512,544) w0dist: o -> (w0[o*66+64], w0[o*66+65])
//   [544,800) w1: row j (j<16), k<16 -> (w1[j*32+2k], w1[j*32+2k+1])
//   [800,864) w2: row o (o<8),  k<8  -> (w2[o*16+2k], w2[o*16+2k+1])
//   [864,868) w3: k<4 -> (w3[2k], w3[2k+1])
__global__ __launch_bounds__(256) void pack_weights(const float* __restrict__ w0,
                                                    const float* __restrict__ w1,
                                                    const float* __restrict__ w2,
                                                    const float* __restrict__ w3,
                                                    unsigned* __restrict__ pw) {
    const int i = blockIdx.x * 256 + threadIdx.x;
    if (i < 512) {
        const int o = i >> 4, k = i & 15;
        pw[i] = f2h2(w0[o * 66 + 32 + 2 * k], w0[o * 66 + 33 + 2 * k]);
    } else if (i < 544) {
        const int o = i - 512;
        pw[i] = f2h2(w0[o * 66 + 64], w0[o * 66 + 65]);
    } else if (i < 800) {
        const int j = (i - 544) >> 4, k = (i - 544) & 15;
        pw[i] = f2h2(w1[j * 32 + 2 * k], w1[j * 32 + 2 * k + 1]);
    } else if (i < 864) {
        const int o = (i - 800) >> 3, k = (i - 800) & 7;
        pw[i] = f2h2(w2[o * 16 + 2 * k], w2[o * 16 + 2 * k + 1]);
    } else if (i < 868) {
        const int k = i - 864;
        pw[i] = f2h2(w3[2 * k], w3[2 * k + 1]);
    }
}

// Pre-pass: ALr[(b*CH+cy)*CW+cx][o] = sum_c w0[o*66+c] * lr[b][c][cy][cx]
// (fp32 weights; runs once, tiny)
__global__ __launch_bounds__(256) void alr_prepass(const float* __restrict__ lr,
                                                   const float* __restrict__ w0,
                                                   float* __restrict__ alr) {
    const int idx = blockIdx.x * 256 + threadIdx.x;  // over BB*CH*CW = 16384
    if (idx >= BB * CH * CW) return;
    const int b = idx / (CH * CW);
    const int cell = idx - b * (CH * CW);
    const float* lp = lr + (size_t)b * CC * CH * CW + cell;
    float lv[32];
#pragma unroll
    for (int c = 0; c < 32; c++) lv[c] = lp[(size_t)c * (CH * CW)];
    float acc[32];
#pragma unroll
    for (int o = 0; o < 32; o++) {
        float a = 0.f;
#pragma unroll
        for (int c = 0; c < 32; c++) a = fmaf(lv[c], w0[o * 66 + c], a);
        acc[o] = a;
    }
    float4* op = (float4*)(alr + (size_t)idx * 32);
#pragma unroll
    for (int j = 0; j < 8; j++)
        op[j] = make_float4(acc[4 * j], acc[4 * j + 1], acc[4 * j + 2], acc[4 * j + 3]);
}

// Main: one thread per hr pixel; block covers a 2(h) x 64(w) tile (128 thr).
//
// R8 post-mortem: more waves didn't help -> not latency-bound. The binder is
// the SCALAR weight path: ~2.8 KB of s_loads per direction per wave (w1
// dominates), refetched 9x because 112 SGPRs can't hold 712 floats. This
// round keeps R7's structure FROZEN and halves the scalar stream: weights
// pre-packed to fp16 pairs (u32 s_loads, fp32 accumulate via cvt/fma_mix).
// w2/w3 (68 u32) are hoisted before the d-loop to stay SGPR-resident.
template <bool PACKED>
__global__ __launch_bounds__(128, 4) void ercm_main(const float* __restrict__ hr,
                                                    const float* __restrict__ lr,
                                                    const float* __restrict__ alr,
                                                    const unsigned* __restrict__ pw,
                                                    const float* __restrict__ w0,
                                                    const float* __restrict__ w1,
                                                    const float* __restrict__ w2,
                                                    const float* __restrict__ w3,
                                                    float* __restrict__ out) {
    __shared__ float s_alr[54 * 36];
    __shared__ float s_lg[9 * 128];

    const int tid = threadIdx.x;
    const int bx = blockIdx.x;  // 0..7    (WW/64)
    const int by = blockIdx.y;  // 0..127  (HH/2)
    const int b = blockIdx.z;   // 0..1
    const int cy0 = by >> 1;
    const int cx0 = bx * 16;

    if (PACKED) {
        for (int i = tid; i < 54 * 32; i += 128) {
            const int c = i & 31, cell = i >> 5;
            const int row = cell / 18, col = cell - row * 18;
            const int gcy = cy0 - 1 + row, gcx = cx0 - 1 + col;
            float v = 0.f;
            if ((unsigned)gcy < (unsigned)CH && (unsigned)gcx < (unsigned)CW)
                v = alr[(((size_t)b * CH + gcy) * CW + gcx) * 32 + c];
            s_alr[cell * 36 + c] = v;
        }
    } else {
        // Fallback if workspace too small: compute ALr tile in-block (fp32).
        for (int i = tid; i < 54 * 32; i += 128) {
            const int o = i & 31, cell = i >> 5;
            const int row = cell / 18, col = cell - row * 18;
            const int gcy = cy0 - 1 + row, gcx = cx0 - 1 + col;
            float a = 0.f;
            if ((unsigned)gcy < (unsigned)CH && (unsigned)gcx < (unsigned)CW) {
                const float* lp = lr + (size_t)b * CC * CH * CW + (size_t)gcy * CW + gcx;
#pragma unroll
                for (int c = 0; c < 32; c++) a = fmaf(lp[(size_t)c * (CH * CW)], w0[o * 66 + c], a);
            }
            s_alr[cell * 36 + o] = a;
        }
    }
    __syncthreads();

    const int tx = tid & 63, ty = tid >> 6;
    const int h = by * 2 + ty, w = bx * 64 + tx;
    const size_t HW = (size_t)HH * WW;

    float hrv[32];
    const float* hp = hr + (size_t)b * CC * HW + (size_t)h * WW + w;
#pragma unroll
    for (int c = 0; c < 32; c++) hrv[c] = hp[(size_t)c * HW];

    float ahr[32];
    if (PACKED) {
#pragma unroll
        for (int o = 0; o < 32; o++) {
            unsigned r[16];
#pragma unroll
            for (int k = 0; k < 16; k++) r[k] = pw[o * 16 + k];
            float a = 0.f;
#pragma unroll
            for (int k = 0; k < 16; k++) {
                a = fmaf(hrv[2 * k], h2f_lo(r[k]), a);
                a = fmaf(hrv[2 * k + 1], h2f_hi(r[k]), a);
            }
            ahr[o] = a;
        }
    } else {
#pragma unroll
        for (int o = 0; o < 32; o++) {
            float a = 0.f;
#pragma unroll
            for (int c = 0; c < 32; c++) a = fmaf(hrv[c], w0[o * 66 + 32 + c], a);
            ahr[o] = a;
        }
    }

    const int xm = w & 3, ym = h & 3;
    const float xv = (float)(xm < 2 ? xm - 2 : xm - 1);  // x = [-2,-1,1,2]
    const float yv = (float)(ym < 2 ? ym - 2 : ym - 1);
    const float x1 = (float)(4 - xm), x2 = (float)(xm + 1);
    const float y1 = (float)(4 - ym), y2 = (float)(ym + 1);
    const int baseCell = (tx >> 2) + 1;

    // Hoist w2/w3 (68 u32) before the d-loop: they are direction-invariant
    // and small enough to stay SGPR-resident across all 9 directions.
    unsigned r2[64], r3[4];
    if (PACKED) {
#pragma unroll
        for (int k = 0; k < 64; k++) r2[k] = pw[800 + k];
#pragma unroll
        for (int k = 0; k < 4; k++) r3[k] = pw[864 + k];
    }

#pragma unroll 1  // keep rolled (the known-good compile shape)
    for (int d = 0; d < 9; d++) {
        const int dh = c_dh[d], dw = c_dw[d];
        const int sel0 = c_s0[d], sel1 = c_s1[d];
        const float d0 = (sel0 == 0) ? xv : ((sel0 == 1) ? x1 : x2);
        const float d1 = (sel1 == 0) ? yv : ((sel1 == 1) ? y1 : y2);
        const bool valid = ((unsigned)(h + 4 * dh) < (unsigned)HH) &&
                           ((unsigned)(w + 4 * dw) < (unsigned)WW);

        const float* ap = s_alr + ((1 + dh) * 18 + baseCell + dw) * 36;
        float v[32];
#pragma unroll
        for (int j = 0; j < 8; j++) {
            const float4 q = ((const float4*)ap)[j];
            v[4 * j + 0] = q.x; v[4 * j + 1] = q.y;
            v[4 * j + 2] = q.z; v[4 * j + 3] = q.w;
        }
        float lg;
        if (PACKED) {
            // layer 1
#pragma unroll
            for (int o = 0; o < 32; o++) {
                const unsigned u = pw[512 + o];
                float t = ahr[o] + v[o];
                t = fmaf(d0, h2f_lo(u), t);
                t = fmaf(d1, h2f_hi(u), t);
                v[o] = fmaxf(t, 0.01f * t);
            }
            // layer 2: 32 -> 16 (w1 rows = 16 contiguous u32 -> batched s_load)
            float h1[16];
#pragma unroll
            for (int o = 0; o < 16; o++) {
                unsigned r[16];
#pragma unroll
                for (int k = 0; k < 16; k++) r[k] = pw[544 + o * 16 + k];
                float a = 0.f;
#pragma unroll
                for (int k = 0; k < 16; k++) {
                    a = fmaf(v[2 * k], h2f_lo(r[k]), a);
                    a = fmaf(v[2 * k + 1], h2f_hi(r[k]), a);
                }
                h1[o] = fmaxf(a, 0.01f * a);
            }
            // layer 3: 16 -> 8 (weights already resident in r2)
            float h2[8];
#pragma unroll
            for (int o = 0; o < 8; o++) {
                float a = 0.f;
#pragma unroll
                for (int k = 0; k < 8; k++) {
                    a = fmaf(h1[2 * k], h2f_lo(r2[o * 8 + k]), a);
                    a = fmaf(h1[2 * k + 1], h2f_hi(r2[o * 8 + k]), a);
                }
                h2[o] = fmaxf(a, 0.01f * a);
            }
            // layer 4: 8 -> 1
            lg = 0.f;
#pragma unroll
            for (int k = 0; k < 4; k++) {
                lg = fmaf(h2[2 * k], h2f_lo(r3[k]), lg);
                lg = fmaf(h2[2 * k + 1], h2f_hi(r3[k]), lg);
            }
        } else {
#pragma unroll
            for (int o = 0; o < 32; o++) {
                float t = ahr[o] + v[o];
                t = fmaf(d0, w0[o * 66 + 64], t);
                t = fmaf(d1, w0[o * 66 + 65], t);
                v[o] = fmaxf(t, 0.01f * t);
            }
            float h1[16];
#pragma unroll
            for (int o = 0; o < 16; o++) {
                float a = 0.f;
#pragma unroll
                for (int c = 0; c < 32; c++) a = fmaf(v[c], w1[o * 32 + c], a);
                h1[o] = fmaxf(a, 0.01f * a);
            }
            float h2[8];
#pragma unroll
            for (int o = 0; o < 8; o++) {
                float a = 0.f;
#pragma unroll
                for (int c = 0; c < 16; c++) a = fmaf(h1[c], w2[o * 16 + c], a);
                h2[o] = fmaxf(a, 0.01f * a);
            }
            lg = 0.f;
#pragma unroll
            for (int c = 0; c < 8; c++) lg = fmaf(h2[c], w3[c], lg);
        }

        s_lg[d * 128 + tid] = valid ? lg : -100.0f;
    }

    // softmax over the 9 direction logits
    float l[9];
#pragma unroll
    for (int d = 0; d < 9; d++) l[d] = s_lg[d * 128 + tid];
    float m = l[0];
#pragma unroll
    for (int d = 1; d < 9; d++) m = fmaxf(m, l[d]);
    float s = 0.f;
#pragma unroll
    for (int d = 0; d < 9; d++) {
        l[d] = __expf(l[d] - m);
        s += l[d];
    }
    const float inv = __builtin_amdgcn_rcpf(s);
    float* op = out + (size_t)b * 9 * HW + (size_t)h * WW + w;
#pragma unroll
    for (int d = 0; d < 9; d++) op[(size_t)d * HW] = l[d] * inv;
}

extern "C" void kernel_launch(void* const* d_in, const int* in_sizes, int n_in,
                              void* d_out, int out_size, void* d_ws, size_t ws_size,
                              hipStream_t stream) {
    const float* lr = (const float*)d_in[0];
    const float* hr = (const float*)d_in[1];
    // d_in[2], d_in[3] (lr_feature_r / hr_feature_r) unused by the reference.
    const float* w0 = (const float*)d_in[4];
    const float* w1 = (const float*)d_in[5];
    const float* w2 = (const float*)d_in[6];
    const float* w3 = (const float*)d_in[7];
    float* out = (float*)d_out;

    const size_t alr_bytes = (size_t)BB * CH * CW * 32 * sizeof(float);  // 2 MB
    const size_t need = alr_bytes + 4096;
    dim3 grid(WW / 64, HH / 2, BB);  // 2048 blocks of 128 thr

    if (ws_size >= need) {
        float* alr = (float*)d_ws;
        unsigned* pw = (unsigned*)((char*)d_ws + alr_bytes);
        pack_weights<<<4, 256, 0, stream>>>(w0, w1, w2, w3, pw);
        alr_prepass<<<(BB * CH * CW + 255) / 256, 256, 0, stream>>>(lr, w0, alr);
        ercm_main<true><<<grid, 128, 0, stream>>>(hr, lr, alr, pw, w0, w1, w2, w3, out);
    } else {
        ercm_main<false><<<grid, 128, 0, stream>>>(hr, lr, nullptr, nullptr, w0, w1, w2, w3, out);
    }
}

// Round 10
// 711.118 us; speedup vs baseline: 3.9650x; 3.9650x over previous
//
#include <hip/hip_runtime.h>
#include <math.h>

#define SC 4
#define BB 2
#define CC 32
#define HH 256
#define WW 512
#define CH (HH / SC)   // 64
#define CW (WW / SC)   // 128

// Direction metadata (output channel order: c, l, r, t, b, lt, rt, lb, rb)
//   s0: 0 -> xv (x[w%4]), 1 -> 4-(w%4) (D1), 2 -> (w%4)+1 (D2)
//   s1: 0 -> yv (x[h%4]), 1 -> 4-(h%4) (D3), 2 -> (h%4)+1 (D4)
// Diagonals reuse D1..D4 which modify ONLY ONE channel each.  [verified R2]
__device__ __constant__ int c_dh[9] = {0, 0, 0, -1, 1, -1, -1, 1, 1};
__device__ __constant__ int c_dw[9] = {0, -1, 1, 0, 0, -1, 1, -1, 1};
__device__ __constant__ int c_s0[9] = {0, 1, 2, 0, 0, 1, 2, 0, 0};
__device__ __constant__ int c_s1[9] = {0, 0, 0, 1, 2, 0, 0, 1, 2};

// Pre-pass: ALr[(b*CH+cy)*CW+cx][o] = sum_c w0[o*66+c] * lr[b][c][cy][cx]
// (R3's exact version -- participates in the good compile; do not touch.)
__global__ __launch_bounds__(256) void alr_prepass(const float* __restrict__ lr,
                                                   const float* __restrict__ w0,
                                                   float* __restrict__ alr) {
    const int idx = blockIdx.x * 256 + threadIdx.x;  // over BB*CH*CW = 16384
    if (idx >= BB * CH * CW) return;
    const int b = idx / (CH * CW);
    const int cell = idx - b * (CH * CW);
    const float* lp = lr + (size_t)b * CC * CH * CW + cell;
    float lv[32];
#pragma unroll
    for (int c = 0; c < 32; c++) lv[c] = lp[(size_t)c * (CH * CW)];
    float acc[32];
#pragma unroll
    for (int o = 0; o < 32; o++) {
        float a = 0.f;
#pragma unroll
        for (int c = 0; c < 32; c++) a = fmaf(lv[c], w0[o * 66 + c], a);
        acc[o] = a;
    }
    float4* op = (float4*)(alr + (size_t)idx * 32);
#pragma unroll
    for (int j = 0; j < 8; j++)
        op[j] = make_float4(acc[4 * j], acc[4 * j + 1], acc[4 * j + 2], acc[4 * j + 3]);
}

// Main: one thread per hr pixel; block covers a 2(h) x 64(w) tile (128 thr).
//
// R8/R9 post-mortem: time scales with per-wave work+traffic, not wave count
// -> throughput-bound on a per-wave resource. Prime suspect: the scalar
// weight stream (~2.8 KB s_loads per direction per wave; 712 floats can't
// persist in 112 SGPRs, so they're re-fetched 9x, with lgkmcnt mixing
// against ds_read). R9's SGPR-array hoist overflowed the SGPR file ->
// scratch catastrophe. This round: weights for layers 1(dist)/2/3/4 staged
// once per block into LDS (2.9 KB) and read as same-address float4
// broadcasts (conflict-free, zero SMEM in the d-loop). Everything else is
// R7 frozen.
template <bool USE_WS>
__global__ __launch_bounds__(128, 4) void ercm_main(const float* __restrict__ hr,
                                                    const float* __restrict__ lr,
                                                    const float* __restrict__ alr,
                                                    const float* __restrict__ w0,
                                                    const float* __restrict__ w1,
                                                    const float* __restrict__ w2,
                                                    const float* __restrict__ w3,
                                                    float* __restrict__ out) {
    // 3 coarse rows x 18 coarse cols of 32-float ALr vectors, padded to 36
    // floats/cell (stride-32 would be a 16-way bank conflict on ds_read_b128;
    // 36 rotates 4 banks/cell -> 2-way broadcast groups, which is free).
    __shared__ float s_alr[54 * 36];
    __shared__ float s_lg[9 * 128];  // per-direction logits (rolled d-loop)
    __shared__ float s_w1[16 * 32];  // 2 KB  (layer-2 weights)
    __shared__ float s_w2[8 * 16];   // 512 B (layer-3)
    __shared__ float s_w3[8];        // 32 B  (layer-4)
    __shared__ float s_w0d[64];      // 256 B (layer-1 distance weights, o-pairs)

    const int tid = threadIdx.x;
    const int bx = blockIdx.x;  // 0..7    (WW/64)
    const int by = blockIdx.y;  // 0..127  (HH/2)
    const int b = blockIdx.z;   // 0..1
    const int cy0 = by >> 1;    // coarse row of both fine rows in this tile
    const int cx0 = bx * 16;

    // ---- stage weights into LDS (per-block; lines are L2/L3-hot) ----
    for (int i = tid; i < 512; i += 128) s_w1[i] = w1[i];
    if (tid < 128) s_w2[tid] = w2[tid];
    if (tid < 8) s_w3[tid] = w3[tid];
    if (tid < 32) {
        s_w0d[2 * tid] = w0[tid * 66 + 64];
        s_w0d[2 * tid + 1] = w0[tid * 66 + 65];
    }

    if (USE_WS) {
        for (int i = tid; i < 54 * 32; i += 128) {
            const int c = i & 31, cell = i >> 5;
            const int row = cell / 18, col = cell - row * 18;
            const int gcy = cy0 - 1 + row, gcx = cx0 - 1 + col;
            float v = 0.f;
            if ((unsigned)gcy < (unsigned)CH && (unsigned)gcx < (unsigned)CW)
                v = alr[(((size_t)b * CH + gcy) * CW + gcx) * 32 + c];
            s_alr[cell * 36 + c] = v;
        }
    } else {
        // Fallback if workspace too small: compute ALr tile in-block.
        for (int i = tid; i < 54 * 32; i += 128) {
            const int o = i & 31, cell = i >> 5;
            const int row = cell / 18, col = cell - row * 18;
            const int gcy = cy0 - 1 + row, gcx = cx0 - 1 + col;
            float a = 0.f;
            if ((unsigned)gcy < (unsigned)CH && (unsigned)gcx < (unsigned)CW) {
                const float* lp = lr + (size_t)b * CC * CH * CW + (size_t)gcy * CW + gcx;
#pragma unroll
                for (int c = 0; c < 32; c++) a = fmaf(lp[(size_t)c * (CH * CW)], w0[o * 66 + c], a);
            }
            s_alr[cell * 36 + o] = a;
        }
    }
    __syncthreads();

    const int tx = tid & 63, ty = tid >> 6;    // ty in {0,1}
    const int h = by * 2 + ty, w = bx * 64 + tx;
    const size_t HW = (size_t)HH * WW;

    // hr channel vector at the center pixel (shared by all 9 directions)
    float hrv[32];
    const float* hp = hr + (size_t)b * CC * HW + (size_t)h * WW + w;
#pragma unroll
    for (int c = 0; c < 32; c++) hrv[c] = hp[(size_t)c * HW];

    // A_hr[o] = sum_c hr[c] * w0[o, 32+c]  (one-shot phase; s_loads fine here)
    float ahr[32];
#pragma unroll
    for (int o = 0; o < 32; o++) {
        float a = 0.f;
#pragma unroll
        for (int c = 0; c < 32; c++) a = fmaf(hrv[c], w0[o * 66 + 32 + c], a);
        ahr[o] = a;
    }

    const int xm = w & 3, ym = h & 3;
    const float xv = (float)(xm < 2 ? xm - 2 : xm - 1);  // x = [-2,-1,1,2]
    const float yv = (float)(ym < 2 ? ym - 2 : ym - 1);
    const float x1 = (float)(4 - xm), x2 = (float)(xm + 1);
    const float y1 = (float)(4 - ym), y2 = (float)(ym + 1);
    const int baseCell = (tx >> 2) + 1;  // local coarse col (+1 halo offset)

    const float4* w1q = (const float4*)s_w1;   // [o*8 + j]
    const float4* w2q = (const float4*)s_w2;   // [o*4 + j]
    const float2* w0dq = (const float2*)s_w0d; // [o]

#pragma unroll 1  // keep rolled (the known-good compile shape)
    for (int d = 0; d < 9; d++) {
        const int dh = c_dh[d], dw = c_dw[d];
        const int sel0 = c_s0[d], sel1 = c_s1[d];
        const float d0 = (sel0 == 0) ? xv : ((sel0 == 1) ? x1 : x2);
        const float d1 = (sel1 == 0) ? yv : ((sel1 == 1) ? y1 : y2);
        const bool valid = ((unsigned)(h + 4 * dh) < (unsigned)HH) &&
                           ((unsigned)(w + 4 * dw) < (unsigned)WW);

        const float* ap = s_alr + ((1 + dh) * 18 + baseCell + dw) * 36;
        float v[32];
#pragma unroll
        for (int j = 0; j < 8; j++) {
            const float4 q = ((const float4*)ap)[j];
            v[4 * j + 0] = q.x; v[4 * j + 1] = q.y;
            v[4 * j + 2] = q.z; v[4 * j + 3] = q.w;
        }
        // layer 1: A_hr + A_lr + distance part, LeakyReLU(0.01)
#pragma unroll
        for (int o = 0; o < 32; o++) {
            const float2 wd = w0dq[o];  // LDS broadcast
            float t = ahr[o] + v[o];
            t = fmaf(d0, wd.x, t);
            t = fmaf(d1, wd.y, t);
            v[o] = fmaxf(t, 0.01f * t);
        }
        // layer 2: 32 -> 16, weights via LDS float4 broadcasts
        float h1[16];
#pragma unroll
        for (int o = 0; o < 16; o++) {
            float a = 0.f;
#pragma unroll
            for (int j = 0; j < 8; j++) {
                const float4 q = w1q[o * 8 + j];
                a = fmaf(v[4 * j + 0], q.x, a);
                a = fmaf(v[4 * j + 1], q.y, a);
                a = fmaf(v[4 * j + 2], q.z, a);
                a = fmaf(v[4 * j + 3], q.w, a);
            }
            h1[o] = fmaxf(a, 0.01f * a);
        }
        // layer 3: 16 -> 8, weights via LDS float4 broadcasts
        float h2[8];
#pragma unroll
        for (int o = 0; o < 8; o++) {
            float a = 0.f;
#pragma unroll
            for (int j = 0; j < 4; j++) {
                const float4 q = w2q[o * 4 + j];
                a = fmaf(h1[4 * j + 0], q.x, a);
                a = fmaf(h1[4 * j + 1], q.y, a);
                a = fmaf(h1[4 * j + 2], q.z, a);
                a = fmaf(h1[4 * j + 3], q.w, a);
            }
            h2[o] = fmaxf(a, 0.01f * a);
        }
        // layer 4: 8 -> 1 (no activation)
        float lg = 0.f;
#pragma unroll
        for (int c = 0; c < 8; c++) lg = fmaf(h2[c], s_w3[c], lg);

        s_lg[d * 128 + tid] = valid ? lg : -100.0f;
    }

    // softmax over the 9 direction logits
    float l[9];
#pragma unroll
    for (int d = 0; d < 9; d++) l[d] = s_lg[d * 128 + tid];
    float m = l[0];
#pragma unroll
    for (int d = 1; d < 9; d++) m = fmaxf(m, l[d]);
    float s = 0.f;
#pragma unroll
    for (int d = 0; d < 9; d++) {
        l[d] = __expf(l[d] - m);
        s += l[d];
    }
    const float inv = __builtin_amdgcn_rcpf(s);
    float* op = out + (size_t)b * 9 * HW + (size_t)h * WW + w;
#pragma unroll
    for (int d = 0; d < 9; d++) op[(size_t)d * HW] = l[d] * inv;
}

extern "C" void kernel_launch(void* const* d_in, const int* in_sizes, int n_in,
                              void* d_out, int out_size, void* d_ws, size_t ws_size,
                              hipStream_t stream) {
    const float* lr = (const float*)d_in[0];
    const float* hr = (const float*)d_in[1];
    // d_in[2], d_in[3] (lr_feature_r / hr_feature_r) are unused by the reference.
    const float* w0 = (const float*)d_in[4];
    const float* w1 = (const float*)d_in[5];
    const float* w2 = (const float*)d_in[6];
    const float* w3 = (const float*)d_in[7];
    float* out = (float*)d_out;

    const size_t alr_bytes = (size_t)BB * CH * CW * 32 * sizeof(float);  // 2 MB
    dim3 grid(WW / 64, HH / 2, BB);  // 8 x 128 x 2 = 2048 blocks of 128 thr

    if (ws_size >= alr_bytes) {
        float* alr = (float*)d_ws;
        alr_prepass<<<(BB * CH * CW + 255) / 256, 256, 0, stream>>>(lr, w0, alr);
        ercm_main<true><<<grid, 128, 0, stream>>>(hr, lr, alr, w0, w1, w2, w3, out);
    } else {
        ercm_main<false><<<grid, 128, 0, stream>>>(hr, lr, nullptr, w0, w1, w2, w3, out);
    }
}

// Round 11
// 161.530 us; speedup vs baseline: 17.4555x; 4.4024x over previous
//
#include <hip/hip_runtime.h>
#include <math.h>

#define SC 4
#define BB 2
#define CC 32
#define HH 256
#define WW 512
#define CH (HH / SC)   // 64
#define CW (WW / SC)   // 128

using f16x8 = __attribute__((ext_vector_type(8))) _Float16;
using f32x4 = __attribute__((ext_vector_type(4))) float;

// Direction metadata (output channel order: c, l, r, t, b, lt, rt, lb, rb)
//   s0: 0 -> xv (x[w%4]), 1 -> 4-(w%4) (D1), 2 -> (w%4)+1 (D2)
//   s1: 0 -> yv (x[h%4]), 1 -> 4-(h%4) (D3), 2 -> (h%4)+1 (D4)
// Diagonals reuse D1..D4 which modify ONLY ONE channel each.  [verified R2]
__device__ __constant__ int c_dh[9] = {0, 0, 0, -1, 1, -1, -1, 1, 1};
__device__ __constant__ int c_dw[9] = {0, -1, 1, 0, 0, -1, 1, -1, 1};
__device__ __constant__ int c_s0[9] = {0, 1, 2, 0, 0, 1, 2, 0, 0};
__device__ __constant__ int c_s1[9] = {0, 0, 0, 1, 2, 0, 0, 1, 2};

// Pre-pass: ALr[(b*CH+cy)*CW+cx][o] = sum_c w0[o*66+c] * lr[b][c][cy][cx]  (fp32)
__global__ __launch_bounds__(256) void alr_prepass(const float* __restrict__ lr,
                                                   const float* __restrict__ w0,
                                                   float* __restrict__ alr) {
    const int idx = blockIdx.x * 256 + threadIdx.x;
    if (idx >= BB * CH * CW) return;
    const int b = idx / (CH * CW);
    const int cell = idx - b * (CH * CW);
    const float* lp = lr + (size_t)b * CC * CH * CW + cell;
    float lv[32];
#pragma unroll
    for (int c = 0; c < 32; c++) lv[c] = lp[(size_t)c * (CH * CW)];
    float acc[32];
#pragma unroll
    for (int o = 0; o < 32; o++) {
        float a = 0.f;
#pragma unroll
        for (int c = 0; c < 32; c++) a = fmaf(lv[c], w0[o * 66 + c], a);
        acc[o] = a;
    }
    float4* op = (float4*)(alr + (size_t)idx * 32);
#pragma unroll
    for (int j = 0; j < 8; j++)
        op[j] = make_float4(acc[4 * j], acc[4 * j + 1], acc[4 * j + 2], acc[4 * j + 3]);
}

// MFMA main. Block = 256 thr = 4 waves; wave ty owns h-row by*4+ty, 64 w-pixels
// (4 M-tiles of 16). All matmul layers via v_mfma_f32_16x16x32_f16 with
// weights resident in B-fragments (24 VGPRs, loaded once). fp32 accumulate;
// f16 only at MFMA operand boundaries. Fragment layouts (guide §3, m89/m120):
//   A[m=lane&15][k=quad*8+j], B[k=quad*8+j][n=lane&15],
//   D[row m=quad*4+reg][col n=lane&15].
// Per-wave LDS buffers glue D->A layout transforms (wave-synchronous, no
// barriers; compiler inserts lgkmcnt waits).
template <bool USE_WS>
__global__ __launch_bounds__(256, 4) void ercm_mfma(const float* __restrict__ hr,
                                                    const float* __restrict__ lr,
                                                    const float* __restrict__ alr,
                                                    const float* __restrict__ w0,
                                                    const float* __restrict__ w1,
                                                    const float* __restrict__ w2,
                                                    const float* __restrict__ w3,
                                                    float* __restrict__ out) {
    __shared__ _Float16 s_alr[54 * 40];     // [cell][o], stride 40 halfs (16B-aligned rows, bank-rotating)
    __shared__ _Float16 s_ahr[4][64 * 40];  // per wave: [px][o]
    __shared__ _Float16 s_d2[4][16 * 24];   // per wave: [m][ch2], stride 24 halfs
    __shared__ float    s_part[4][64 * 12]; // per wave: [px][ch3], stride 12 words
    __shared__ float    s_lg[9][256];       // logits (d is runtime in rolled loop)

    const int tid = threadIdx.x;
    const int lane = tid & 63;
    const int ty = tid >> 6;       // wave id = h-row within block
    const int m16 = lane & 15;
    const int q = lane >> 4;       // quad
    const int bx = blockIdx.x;     // 0..7
    const int by = blockIdx.y;     // 0..63
    const int b = blockIdx.z;      // 0..1
    const int h = by * 4 + ty;
    const int wp0 = bx * 64;
    const size_t HW = (size_t)HH * WW;

    // ---- stage ALr halo tile (3 x 18 coarse cells), f16 ----
    const int cy0 = by, cx0 = bx * 16;
    if (USE_WS) {
        for (int i = tid; i < 54 * 32; i += 256) {
            const int c = i & 31, cell = i >> 5;
            const int row = cell / 18, col = cell - row * 18;
            const int gcy = cy0 - 1 + row, gcx = cx0 - 1 + col;
            float v = 0.f;
            if ((unsigned)gcy < (unsigned)CH && (unsigned)gcx < (unsigned)CW)
                v = alr[(((size_t)b * CH + gcy) * CW + gcx) * 32 + c];
            s_alr[cell * 40 + c] = (_Float16)v;
        }
    } else {
        for (int i = tid; i < 54 * 32; i += 256) {
            const int o = i & 31, cell = i >> 5;
            const int row = cell / 18, col = cell - row * 18;
            const int gcy = cy0 - 1 + row, gcx = cx0 - 1 + col;
            float a = 0.f;
            if ((unsigned)gcy < (unsigned)CH && (unsigned)gcx < (unsigned)CW) {
                const float* lp = lr + (size_t)b * CC * CH * CW + (size_t)gcy * CW + gcx;
#pragma unroll
                for (int c = 0; c < 32; c++) a = fmaf(lp[(size_t)c * (CH * CW)], w0[o * 66 + c], a);
            }
            s_alr[cell * 40 + o] = (_Float16)a;
        }
    }

    // ---- load weight B-fragments (once; 24 VGPRs live, w0h dies after Phase A) ----
    f16x8 w1B, w0hB0, w0hB1, w2B;
    {
        const float* p1 = w1 + m16 * 32 + q * 8;
        const float* p00 = w0 + m16 * 66 + 32 + q * 8;
        const float* p01 = w0 + (m16 + 16) * 66 + 32 + q * 8;
        const bool w2ok = (m16 < 8) && (q < 2);
#pragma unroll
        for (int j = 0; j < 8; j++) {
            w1B[j] = (_Float16)p1[j];
            w0hB0[j] = (_Float16)p00[j];
            w0hB1[j] = (_Float16)p01[j];
            w2B[j] = (_Float16)(w2ok ? w2[m16 * 16 + q * 8 + j] : 0.f);
        }
    }
    float w0d0[8], w0d1[8];  // layer-1 distance weights for this lane's channels o=q*8+j
#pragma unroll
    for (int j = 0; j < 8; j++) {
        w0d0[j] = w0[(q * 8 + j) * 66 + 64];
        w0d1[j] = w0[(q * 8 + j) * 66 + 65];
    }
    const float w3v = (m16 < 8) ? w3[m16] : 0.f;

    // ---- Phase A: ahr = hr . w0hr via MFMA, staged to s_ahr[px][o] (f16) ----
    const float* hp = hr + (size_t)b * CC * HW + (size_t)h * WW + wp0;
#pragma unroll 1
    for (int t = 0; t < 4; t++) {
        const int px = t * 16 + m16;
        f16x8 a;
#pragma unroll
        for (int j = 0; j < 8; j++) a[j] = (_Float16)hp[(size_t)(q * 8 + j) * HW + px];
        f32x4 acc0 = {0.f, 0.f, 0.f, 0.f}, acc1 = {0.f, 0.f, 0.f, 0.f};
        acc0 = __builtin_amdgcn_mfma_f32_16x16x32_f16(a, w0hB0, acc0, 0, 0, 0);
        acc1 = __builtin_amdgcn_mfma_f32_16x16x32_f16(a, w0hB1, acc1, 0, 0, 0);
#pragma unroll
        for (int r = 0; r < 4; r++) {
            const int pxr = t * 16 + q * 4 + r;  // D row = pixel-in-tile
            s_ahr[ty][pxr * 40 + m16] = (_Float16)acc0[r];        // D col = ch 0..15
            s_ahr[ty][pxr * 40 + 16 + m16] = (_Float16)acc1[r];   // ch 16..31
        }
    }

    // per-lane distance operand values (pixel phase xm = m16&3 for A1 build)
    const int xm = m16 & 3;
    const float xv = (float)(xm < 2 ? xm - 2 : xm - 1);
    const float x1 = (float)(4 - xm), x2 = (float)(xm + 1);
    const int ym = h & 3;
    const float yv = (float)(ym < 2 ? ym - 2 : ym - 1);
    const float y1 = (float)(4 - ym), y2 = (float)(ym + 1);

    __syncthreads();  // s_alr staged (s_ahr is per-wave, already ordered)

#pragma unroll 1
    for (int d = 0; d < 9; d++) {
        const int dh = c_dh[d], dw = c_dw[d];
        const int sel0 = c_s0[d], sel1 = c_s1[d];
        const float d0 = (sel0 == 0) ? xv : ((sel0 == 1) ? x1 : x2);  // per-lane
        const float d1 = (sel1 == 0) ? yv : ((sel1 == 1) ? y1 : y2);  // wave-uniform

#pragma unroll 1
        for (int t = 0; t < 4; t++) {
            // layer 1: A1[m=pixel][k=o] = leaky(ahr + alr + d0*w0d0 + d1*w0d1)
            const int pxm = t * 16 + m16;
            const int cell = (1 + dh) * 18 + (1 + dw + (pxm >> 2));
            const f16x8 ah = *(const f16x8*)&s_ahr[ty][pxm * 40 + q * 8];
            const f16x8 al = *(const f16x8*)&s_alr[cell * 40 + q * 8];
            f16x8 a1;
#pragma unroll
            for (int j = 0; j < 8; j++) {
                float v = (float)ah[j] + (float)al[j];
                v = fmaf(d0, w0d0[j], v);
                v = fmaf(d1, w0d1[j], v);
                v = fmaxf(v, 0.01f * v);
                a1[j] = (_Float16)v;
            }
            // layer 2 (K=32): one MFMA
            f32x4 acc2 = {0.f, 0.f, 0.f, 0.f};
            acc2 = __builtin_amdgcn_mfma_f32_16x16x32_f16(a1, w1B, acc2, 0, 0, 0);
            // leaky + stage D2 -> A3 layout via per-wave LDS
#pragma unroll
            for (int r = 0; r < 4; r++) {
                float v = acc2[r];
                v = fmaxf(v, 0.01f * v);
                s_d2[ty][(q * 4 + r) * 24 + m16] = (_Float16)v;
            }
            f16x8 a3;
#pragma unroll
            for (int j = 0; j < 8; j++) a3[j] = (_Float16)0.f;
            if (q < 2) a3 = *(const f16x8*)&s_d2[ty][m16 * 24 + q * 8];  // k=ch2 0..15, pad 16..31
            // layer 3 (K=16 padded to 32, N=8 padded to 16): one MFMA
            f32x4 acc3 = {0.f, 0.f, 0.f, 0.f};
            acc3 = __builtin_amdgcn_mfma_f32_16x16x32_f16(a3, w2B, acc3, 0, 0, 0);
            // layer 4 partials: w3[ch3]*leaky(h2) -> s_part[px][ch3]
            if (m16 < 8) {
#pragma unroll
                for (int r = 0; r < 4; r++) {
                    float v = acc3[r];
                    v = fmaxf(v, 0.01f * v);
                    s_part[ty][(t * 16 + q * 4 + r) * 12 + m16] = w3v * v;
                }
            }
        }
        // layer-4 gather: lane = wave-local pixel
        const float4 p0 = *(const float4*)&s_part[ty][lane * 12];
        const float4 p1 = *(const float4*)&s_part[ty][lane * 12 + 4];
        const float lg = ((p0.x + p0.y) + (p0.z + p0.w)) + ((p1.x + p1.y) + (p1.z + p1.w));
        const int wpix = wp0 + lane;
        const bool valid = ((unsigned)(h + 4 * dh) < (unsigned)HH) &&
                           ((unsigned)(wpix + 4 * dw) < (unsigned)WW);
        s_lg[d][tid] = valid ? lg : -100.0f;
    }

    // softmax over the 9 direction logits (own thread's values; no barrier)
    float l[9];
#pragma unroll
    for (int d = 0; d < 9; d++) l[d] = s_lg[d][tid];
    float m = l[0];
#pragma unroll
    for (int d = 1; d < 9; d++) m = fmaxf(m, l[d]);
    float s = 0.f;
#pragma unroll
    for (int d = 0; d < 9; d++) {
        l[d] = __expf(l[d] - m);
        s += l[d];
    }
    const float inv = __builtin_amdgcn_rcpf(s);
    float* op = out + (size_t)b * 9 * HW + (size_t)h * WW + wp0 + lane;
#pragma unroll
    for (int d = 0; d < 9; d++) op[(size_t)d * HW] = l[d] * inv;
}

extern "C" void kernel_launch(void* const* d_in, const int* in_sizes, int n_in,
                              void* d_out, int out_size, void* d_ws, size_t ws_size,
                              hipStream_t stream) {
    const float* lr = (const float*)d_in[0];
    const float* hr = (const float*)d_in[1];
    // d_in[2], d_in[3] (lr_feature_r / hr_feature_r) are unused by the reference.
    const float* w0 = (const float*)d_in[4];
    const float* w1 = (const float*)d_in[5];
    const float* w2 = (const float*)d_in[6];
    const float* w3 = (const float*)d_in[7];
    float* out = (float*)d_out;

    const size_t alr_bytes = (size_t)BB * CH * CW * 32 * sizeof(float);  // 2 MB
    dim3 grid(WW / 64, HH / 4, BB);  // 1024 blocks of 256 thr (4 waves)

    if (ws_size >= alr_bytes) {
        float* alr = (float*)d_ws;
        alr_prepass<<<(BB * CH * CW + 255) / 256, 256, 0, stream>>>(lr, w0, alr);
        ercm_mfma<true><<<grid, 256, 0, stream>>>(hr, lr, alr, w0, w1, w2, w3, out);
    } else {
        ercm_mfma<false><<<grid, 256, 0, stream>>>(hr, lr, nullptr, w0, w1, w2, w3, out);
    }
}